// Round 1
// 401.866 us; speedup vs baseline: 1.0548x; 1.0548x over previous
//
#include <hip/hip_runtime.h>
#include <math.h>

#define HIDDEN 512
#define BATCH  16
#define NN     2048
#define CH     8   // h-split chunks in the output GEMV

// Kernel 1: fused degree + row-0 weight. One WAVE per adjacency row (b,m):
// 64 lanes x 8 float4 = 2048 floats, pure wave shuffle reduce (no LDS, no barrier).
//   dval   = 1/sqrt( sum_k relu(adj[b,m,k]) + 1 )
//   w0[b,m]= (relu(adj[b,0,m]) + (m==0)) * dval     // d[b,0] factor folded into y later
//   d0[b]  = dval  (for m==0)
__global__ __launch_bounds__(256) void k_deg_w0(const float* __restrict__ adj,
                                                float* __restrict__ w0,
                                                float* __restrict__ d0) {
    const int gw   = (blockIdx.x * 256 + threadIdx.x) >> 6;   // global wave id = row
    const int lane = threadIdx.x & 63;
    const int b = gw >> 11;                                   // / NN
    const int m = gw & (NN - 1);
    // row-0 entry for this column: same address across the wave -> broadcast load.
    // Issued first so its latency hides under the streaming reads.
    const float a0 = fmaxf(adj[(size_t)b * NN * NN + m], 0.f);
    const float4* a4 = (const float4*)(adj + (size_t)gw * NN);
    float s = 0.f;
    #pragma unroll
    for (int i = 0; i < 8; ++i) {
        float4 v = a4[lane + 64 * i];
        s += fmaxf(v.x, 0.f) + fmaxf(v.y, 0.f) + fmaxf(v.z, 0.f) + fmaxf(v.w, 0.f);
    }
    #pragma unroll
    for (int off = 32; off; off >>= 1) s += __shfl_down(s, off);
    if (lane == 0) {
        const float dval = 1.0f / sqrtf(s + 1.0f);
        if (m == 0) d0[b] = dval;
        w0[gw] = (m == 0 ? a0 + 1.0f : a0) * dval;
    }
}

// Kernel 2: y[b,h] = d0[b] * sum_m w0[b,m] * feat[b,h,m]
// One WAVE per (b,h) row; feat row contiguous; w0[b,:] is 8 KB, L2-hot.
__global__ __launch_bounds__(256) void k_y(const float* __restrict__ feat,
                                           const float* __restrict__ w0,
                                           const float* __restrict__ d0,
                                           float* __restrict__ y) {
    const int gw   = (blockIdx.x * 256 + threadIdx.x) >> 6;   // 0 .. B*H-1
    const int lane = threadIdx.x & 63;
    const int b = gw >> 9;                                    // / HIDDEN
    const float4* f4 = (const float4*)(feat + (size_t)gw * NN);
    const float4* w4 = (const float4*)(w0 + b * NN);
    float s = 0.f;
    #pragma unroll
    for (int i = 0; i < 8; ++i) {
        float4 f = f4[lane + 64 * i];
        float4 w = w4[lane + 64 * i];
        s += f.x * w.x + f.y * w.y + f.z * w.z + f.w * w.w;
    }
    #pragma unroll
    for (int off = 32; off; off >>= 1) s += __shfl_down(s, off);
    if (lane == 0) y[gw] = d0[b] * s;
}

// Kernel 3: h-split GEMV partials. Grid = B*CH blocks (128), each block handles
// one (b, h-chunk of 64) over all 512 k (2 k per thread). 64-deep loop instead
// of 512 -> 4x more blocks in flight, latency-bound tail removed.
__global__ __launch_bounds__(256) void k_outp(const float* __restrict__ W,
                                              const float* __restrict__ y,
                                              float* __restrict__ part) {
    const int b = blockIdx.x >> 3;          // / CH
    const int c = blockIdx.x & (CH - 1);
    const int t = threadIdx.x;
    const float* yb = y + b * HIDDEN + c * (HIDDEN / CH);
    const float* Wp = W + (size_t)c * (HIDDEN / CH) * HIDDEN;
    float s0 = 0.f, s1 = 0.f;
    #pragma unroll 8
    for (int h = 0; h < HIDDEN / CH; ++h) {
        const float yv = yb[h];                       // wave-uniform broadcast
        s0 += yv * Wp[h * HIDDEN + t];                // coalesced over k
        s1 += yv * Wp[h * HIDDEN + t + 256];
    }
    float* pp = part + (size_t)(b * CH + c) * HIDDEN;
    pp[t] = s0;
    pp[t + 256] = s1;
}

// Kernel 4: combine partials + bias + tanh. 8192 threads, trivial.
__global__ __launch_bounds__(256) void k_outf(const float* __restrict__ part,
                                              const float* __restrict__ bias,
                                              float* __restrict__ out) {
    const int i = blockIdx.x * 256 + threadIdx.x;     // 0 .. B*H-1
    const int b = i >> 9;
    const int k = i & (HIDDEN - 1);
    float s = bias[i];
    #pragma unroll
    for (int c = 0; c < CH; ++c) s += part[(size_t)(b * CH + c) * HIDDEN + k];
    out[i] = tanhf(s);
}

extern "C" void kernel_launch(void* const* d_in, const int* in_sizes, int n_in,
                              void* d_out, int out_size, void* d_ws, size_t ws_size,
                              hipStream_t stream) {
    const float* feat = (const float*)d_in[0];   // [B, H, N]
    const float* adj  = (const float*)d_in[1];   // [B, N, N]
    const float* W    = (const float*)d_in[2];   // [H, H]
    const float* bias = (const float*)d_in[3];   // [B, H]
    float* out = (float*)d_out;                  // [B, H]

    float* w0   = (float*)d_ws;                  // B*N
    float* d0   = w0 + BATCH * NN;               // B (padded slot of 64)
    float* y    = d0 + 64;                       // B*H
    float* part = y + BATCH * HIDDEN;            // B*CH*H

    k_deg_w0<<<(BATCH * NN) / 4, 256, 0, stream>>>(adj, w0, d0);
    k_y<<<(BATCH * HIDDEN) / 4, 256, 0, stream>>>(feat, w0, d0, y);
    k_outp<<<BATCH * CH, 256, 0, stream>>>(W, y, part);
    k_outf<<<(BATCH * HIDDEN) / 256, 256, 0, stream>>>(part, bias, out);
}

// Round 2
// 373.810 us; speedup vs baseline: 1.1339x; 1.0751x over previous
//
#include <hip/hip_runtime.h>
#include <math.h>

#define HIDDEN 512
#define BATCH  16
#define NN     2048
#define CH     16  // h-split chunks in the output GEMV

typedef float v4f __attribute__((ext_vector_type(4)));

// Non-temporal float4 load: stream-once data, don't pollute L2/L3.
__device__ __forceinline__ v4f ntload4(const float* p) {
    return __builtin_nontemporal_load((const v4f*)p);
}

// Kernel 1: fused degree + row-0 weight. One WAVE per adjacency row (b,m):
// 64 lanes x 8 float4 = 2048 floats, pure wave shuffle reduce (no LDS, no barrier).
//   dval   = 1/sqrt( sum_k relu(adj[b,m,k]) + 1 )
//   w0[b,m]= (relu(adj[b,0,m]) + (m==0)) * dval     // d[b,0] factor folded into y later
//   d0[b]  = dval  (for m==0)
__global__ __launch_bounds__(256) void k_deg_w0(const float* __restrict__ adj,
                                                float* __restrict__ w0,
                                                float* __restrict__ d0) {
    const int gw   = (blockIdx.x * 256 + threadIdx.x) >> 6;   // global wave id = row
    const int lane = threadIdx.x & 63;
    const int b = gw >> 11;                                   // / NN
    const int m = gw & (NN - 1);
    // row-0 entry for this column: same 8KB region for all waves of batch b -> L2-hot.
    const float a0 = fmaxf(adj[(size_t)b * NN * NN + m], 0.f);
    const float* arow = adj + (size_t)gw * NN;
    float s = 0.f;
    #pragma unroll
    for (int i = 0; i < 8; ++i) {
        v4f v = ntload4(arow + 4 * (lane + 64 * i));          // streamed, read-once
        s += fmaxf(v.x, 0.f) + fmaxf(v.y, 0.f) + fmaxf(v.z, 0.f) + fmaxf(v.w, 0.f);
    }
    #pragma unroll
    for (int off = 32; off; off >>= 1) s += __shfl_down(s, off);
    if (lane == 0) {
        const float dval = 1.0f / sqrtf(s + 1.0f);
        if (m == 0) d0[b] = dval;
        w0[gw] = (m == 0 ? a0 + 1.0f : a0) * dval;
    }
}

// Kernel 2: y[b,h] = d0[b] * sum_m w0[b,m] * feat[b,h,m]
// One WAVE per (b,h) row; feat streamed non-temporally; w0[b,:] is 8 KB, L2-hot.
__global__ __launch_bounds__(256) void k_y(const float* __restrict__ feat,
                                           const float* __restrict__ w0,
                                           const float* __restrict__ d0,
                                           float* __restrict__ y) {
    const int gw   = (blockIdx.x * 256 + threadIdx.x) >> 6;   // 0 .. B*H-1
    const int lane = threadIdx.x & 63;
    const int b = gw >> 9;                                    // / HIDDEN
    const float* frow = feat + (size_t)gw * NN;
    const float4* w4 = (const float4*)(w0 + b * NN);
    float s = 0.f;
    #pragma unroll
    for (int i = 0; i < 8; ++i) {
        v4f f = ntload4(frow + 4 * (lane + 64 * i));          // streamed, read-once
        float4 w = w4[lane + 64 * i];                         // L2-resident
        s += f.x * w.x + f.y * w.y + f.z * w.z + f.w * w.w;
    }
    #pragma unroll
    for (int off = 32; off; off >>= 1) s += __shfl_down(s, off);
    if (lane == 0) y[gw] = d0[b] * s;
}

// Kernel 3: h-split GEMV partials. Grid = B*CH blocks (256), each block handles
// one (b, h-chunk of 32) over all 512 k (2 k per thread). 32-deep loop keeps the
// latency-bound tail short; W chunks are L2-shared across the 16 blocks per c.
__global__ __launch_bounds__(256) void k_outp(const float* __restrict__ W,
                                              const float* __restrict__ y,
                                              float* __restrict__ part) {
    const int b = blockIdx.x >> 4;          // / CH
    const int c = blockIdx.x & (CH - 1);
    const int t = threadIdx.x;
    const float* yb = y + b * HIDDEN + c * (HIDDEN / CH);
    const float* Wp = W + (size_t)c * (HIDDEN / CH) * HIDDEN;
    float s0 = 0.f, s1 = 0.f;
    #pragma unroll 8
    for (int h = 0; h < HIDDEN / CH; ++h) {
        const float yv = yb[h];                       // wave-uniform broadcast
        s0 += yv * Wp[h * HIDDEN + t];                // coalesced over k
        s1 += yv * Wp[h * HIDDEN + t + 256];
    }
    float* pp = part + (size_t)(b * CH + c) * HIDDEN;
    pp[t] = s0;
    pp[t + 256] = s1;
}

// Kernel 4: combine partials + bias + tanh. 8192 threads, trivial.
__global__ __launch_bounds__(256) void k_outf(const float* __restrict__ part,
                                              const float* __restrict__ bias,
                                              float* __restrict__ out) {
    const int i = blockIdx.x * 256 + threadIdx.x;     // 0 .. B*H-1
    const int b = i >> 9;
    const int k = i & (HIDDEN - 1);
    float s = bias[i];
    #pragma unroll
    for (int c = 0; c < CH; ++c) s += part[(size_t)(b * CH + c) * HIDDEN + k];
    out[i] = tanhf(s);
}

extern "C" void kernel_launch(void* const* d_in, const int* in_sizes, int n_in,
                              void* d_out, int out_size, void* d_ws, size_t ws_size,
                              hipStream_t stream) {
    const float* feat = (const float*)d_in[0];   // [B, H, N]
    const float* adj  = (const float*)d_in[1];   // [B, N, N]
    const float* W    = (const float*)d_in[2];   // [H, H]
    const float* bias = (const float*)d_in[3];   // [B, H]
    float* out = (float*)d_out;                  // [B, H]

    float* w0   = (float*)d_ws;                  // B*N
    float* d0   = w0 + BATCH * NN;               // B (padded slot of 64)
    float* y    = d0 + 64;                       // B*H
    float* part = y + BATCH * HIDDEN;            // B*CH*H

    k_deg_w0<<<(BATCH * NN) / 4, 256, 0, stream>>>(adj, w0, d0);
    k_y<<<(BATCH * HIDDEN) / 4, 256, 0, stream>>>(feat, w0, d0, y);
    k_outp<<<BATCH * CH, 256, 0, stream>>>(W, y, part);
    k_outf<<<(BATCH * HIDDEN) / 256, 256, 0, stream>>>(part, bias, out);
}